// Round 1
// baseline (221.595 us; speedup 1.0000x reference)
//
#include <hip/hip_runtime.h>
#include <hip/hip_bf16.h>
#include <stdint.h>

// Problem: B=16, N=4096, H=512, K=2H=1024
//   pf[b,n,h]   = sum_k features[b,n,k] * Wf[h,k]          (main GEMM, M=65536)
//   pq[b,h]     = sum_k query[b,k] * Wq[h,k]               (tiny GEMM)
//   u[b,n]      = sum_h v[h] * tanh(pf[b,n,h] + pq[b,h])
//   logits[b,n] = 10 * tanh(u[b,n])
// Outputs concat: pf (33554432 f32) then logits (65536 f32).
// Strategy: bf16 MFMA (threshold is bf16-scale), 128x512 tile so features are
// read from HBM exactly once; fused epilogue computes deterministic u-partials.

#define MROWS 65536
#define KDIM  1024
#define HDIM  512

typedef short bf16x8 __attribute__((ext_vector_type(8)));
typedef float f32x4  __attribute__((ext_vector_type(4)));

__device__ __forceinline__ float fast_tanh(float x) {
    float ax = fabsf(x);
    float e  = __expf(-2.0f * ax);      // exp(-2|x|), underflows to 0 for big |x|
    float r  = (1.0f - e) / (1.0f + e);
    return copysignf(r, x);
}

__device__ __forceinline__ unsigned short f2bf(float x) {
    unsigned int u = __builtin_bit_cast(unsigned int, x);
    u += 0x7fffu + ((u >> 16) & 1u);    // round-to-nearest-even
    return (unsigned short)(u >> 16);
}

__device__ __forceinline__ bf16x8 cvt8(float4 a, float4 b) {
    bf16x8 o;
    o[0] = (short)f2bf(a.x); o[1] = (short)f2bf(a.y);
    o[2] = (short)f2bf(a.z); o[3] = (short)f2bf(a.w);
    o[4] = (short)f2bf(b.x); o[5] = (short)f2bf(b.y);
    o[6] = (short)f2bf(b.z); o[7] = (short)f2bf(b.w);
    return o;
}

// ---------------- tiny GEMM: pq[b,h] ----------------
__global__ void pq_kernel(const float* __restrict__ query,
                          const float* __restrict__ Wq,
                          float* __restrict__ pq) {
    const int t = blockIdx.x * blockDim.x + threadIdx.x;   // 8192 threads
    const int b = t >> 9, h = t & 511;
    const float4* q  = (const float4*)(query + (b << 9));
    const float4* wq = (const float4*)(Wq + ((size_t)h << 9));
    float s = 0.0f;
    #pragma unroll 4
    for (int i = 0; i < 128; ++i) {
        float4 a = q[i], c = wq[i];
        s += a.x * c.x + a.y * c.y + a.z * c.z + a.w * c.w;
    }
    pq[t] = s;
}

// ---------------- main GEMM + fused epilogue ----------------
// Block: 512 threads = 8 waves (2m x 4n). Tile: 128 rows x 512 cols, BK=32.
// LDS: double-buffered [A:128x32 + B:512x32] bf16, XOR-swizzled (row&7)<<4.
__global__ __launch_bounds__(512, 2) void gemm_kernel(
    const float* __restrict__ A, const float* __restrict__ Wf,
    const float* __restrict__ pq, const float* __restrict__ v,
    float* __restrict__ pf, float* __restrict__ upart)
{
    __shared__ __align__(16) char lds[2][40960];   // 8KB A + 32KB B per buffer
    const int t    = threadIdx.x;
    const int lane = t & 63;
    const int w    = t >> 6;
    const int wm   = w >> 2;     // 0..1 -> m offset 64*wm
    const int wn   = w & 3;      // 0..3 -> n offset 128*wn
    const int Mbase = blockIdx.x * 128;

    // ---- staging indices: thread t loads 8 floats of A row sm, 4x8 of B ----
    const int sm = t >> 2;            // 0..127
    const int sk = (t & 3) * 8;       // 0,8,16,24
    const float* ag = A  + (size_t)(Mbase + sm) * KDIM + sk;
    const float* bg = Wf + (size_t)sm * KDIM + sk;
    const int wA = (sm * 64 + sk * 2) ^ ((sm & 7) << 4);   // swizzled LDS byte off

    // ---- fragment read offsets ----
    const int fm  = lane & 15;
    const int fk  = (lane >> 4) * 8;
    const int swz = (fm & 7) << 4;
    const int a0  = wm * 4096 + ((fm * 64 + fk * 2) ^ swz);
    const int b0  = 8192 + wn * 8192 + ((fm * 64 + fk * 2) ^ swz);

    f32x4 acc[4][8];
    const f32x4 zf = {0.0f, 0.0f, 0.0f, 0.0f};
    #pragma unroll
    for (int f = 0; f < 4; ++f)
        #pragma unroll
        for (int g = 0; g < 8; ++g) acc[f][g] = zf;

    float4 r[10];

    #define STAGE_LOAD(kt) do {                                              \
        const float* a_ = ag + (kt) * 32;                                    \
        r[0] = *(const float4*)(a_); r[1] = *(const float4*)(a_ + 4);        \
        const float* b_ = bg + (kt) * 32;                                    \
        _Pragma("unroll")                                                    \
        for (int p = 0; p < 4; ++p) {                                        \
            r[2 + 2 * p] = *(const float4*)(b_ + p * 131072);                \
            r[3 + 2 * p] = *(const float4*)(b_ + p * 131072 + 4);            \
        }                                                                    \
    } while (0)

    #define STAGE_WRITE(buf) do {                                            \
        char* base_ = lds[buf];                                              \
        *(bf16x8*)(base_ + wA) = cvt8(r[0], r[1]);                           \
        _Pragma("unroll")                                                    \
        for (int p = 0; p < 4; ++p)                                          \
            *(bf16x8*)(base_ + 8192 + p * 8192 + wA) =                       \
                cvt8(r[2 + 2 * p], r[3 + 2 * p]);                            \
    } while (0)

    STAGE_LOAD(0);
    STAGE_WRITE(0);
    __syncthreads();

    for (int kt = 0; kt < 32; ++kt) {
        const int cur = kt & 1;
        if (kt < 31) STAGE_LOAD(kt + 1);       // issue early: latency hides under MFMA
        const char* base = lds[cur];
        bf16x8 af[4], bfr[8];
        #pragma unroll
        for (int f = 0; f < 4; ++f) af[f]  = *(const bf16x8*)(base + a0 + f * 1024);
        #pragma unroll
        for (int g = 0; g < 8; ++g) bfr[g] = *(const bf16x8*)(base + b0 + g * 1024);
        #pragma unroll
        for (int f = 0; f < 4; ++f)
            #pragma unroll
            for (int g = 0; g < 8; ++g)
                acc[f][g] = __builtin_amdgcn_mfma_f32_16x16x32_bf16(
                    af[f], bfr[g], acc[f][g], 0, 0, 0);
        if (kt < 31) STAGE_WRITE(cur ^ 1);     // write-late after loads land
        __syncthreads();
    }

    // ---- fused epilogue: store pf, accumulate u-partials ----
    const int bidx = Mbase >> 12;              // batch index (128 | 4096)
    const float* pqb = pq + (bidx << 9);
    float vv[8], pv[8];
    #pragma unroll
    for (int g = 0; g < 8; ++g) {
        const int c = wn * 128 + g * 16 + fm;
        vv[g] = v[c];
        pv[g] = pqb[c];
    }
    const int rq = (lane >> 4) * 4;
    #pragma unroll
    for (int f = 0; f < 4; ++f) {
        #pragma unroll
        for (int rr = 0; rr < 4; ++rr) {
            const int row = Mbase + wm * 64 + f * 16 + rq + rr;
            float* prow = pf + (size_t)row * HDIM + wn * 128 + fm;
            float s = 0.0f;
            #pragma unroll
            for (int g = 0; g < 8; ++g) {
                const float val = acc[f][g][rr];
                prow[g * 16] = val;
                s += vv[g] * fast_tanh(val + pv[g]);
            }
            s += __shfl_xor(s, 1);
            s += __shfl_xor(s, 2);
            s += __shfl_xor(s, 4);
            s += __shfl_xor(s, 8);
            if (fm == 0) upart[wn * MROWS + row] = s;   // deterministic slot
        }
    }
}

// ---------------- finish: u = sum of 4 partials, logits = 10*tanh(u) ----------------
__global__ void finish_kernel(const float* __restrict__ upart,
                              float* __restrict__ logits) {
    const int i = blockIdx.x * blockDim.x + threadIdx.x;   // 65536
    const float u = upart[i] + upart[MROWS + i] + upart[2 * MROWS + i] + upart[3 * MROWS + i];
    logits[i] = 10.0f * fast_tanh(u);
}

extern "C" void kernel_launch(void* const* d_in, const int* in_sizes, int n_in,
                              void* d_out, int out_size, void* d_ws, size_t ws_size,
                              hipStream_t stream) {
    const float* features = (const float*)d_in[0];   // [16,4096,1024]
    const float* query    = (const float*)d_in[1];   // [16,1,512]
    const float* Wf       = (const float*)d_in[2];   // [512,1024]
    const float* Wq       = (const float*)d_in[3];   // [512,512]
    const float* v        = (const float*)d_in[4];   // [512]

    float* pf     = (float*)d_out;                   // 33554432 floats
    float* logits = (float*)d_out + 33554432;        // 65536 floats

    float* ws_pq    = (float*)d_ws;                  // 8192 floats
    float* ws_upart = (float*)d_ws + 8192;           // 4*65536 floats

    pq_kernel<<<16, 512, 0, stream>>>(query, Wq, ws_pq);
    gemm_kernel<<<512, 512, 0, stream>>>(features, Wf, ws_pq, v, pf, ws_upart);
    finish_kernel<<<256, 256, 0, stream>>>(ws_upart, logits);
}